// Round 1
// baseline (130.349 us; speedup 1.0000x reference)
//
#include <hip/hip_runtime.h>
#include <hip/hip_bf16.h>
#include <float.h>

// Problem: N=2048, F=64, K=8
//   out[m,0,f]   = x[m,f]
//   out[m,1+j,f] = j-th largest over n of adj[n,m]*x[n,f], sorted descending
//
// Algorithm: adj in [0,1) => only n with x[n,f] > c can produce a product
// beating a top-8 floor t >= c. Use fixed c=1.3 to build per-f candidate
// lists (~200 of 2048), compute top-8 from candidates only, verify t >= c
// per (m,f); rare failures re-done exactly by a full-scan fixup kernel.

#define NN 2048
#define FF 64
#define KK 8
#define CTHRESH 1.3f
#define CAND_CAP 512

__device__ int   g_cand_idx[FF][CAND_CAP];
__device__ float g_cand_val[FF][CAND_CAP];
__device__ int   g_cand_cnt[FF];
__device__ int   g_fail_list[NN * FF];
__device__ int   g_nfail;

// ---------------- Kernel 1: build per-feature candidate lists ----------------
__global__ __launch_bounds__(256) void build_cand(const float* __restrict__ x) {
    int f = blockIdx.x;
    if (f == 0 && threadIdx.x == 0) g_nfail = 0;
    if (threadIdx.x == 0) g_cand_cnt[f] = 0;
    __syncthreads();
    for (int n = threadIdx.x; n < NN; n += 256) {
        float v = x[n * FF + f];
        if (v > CTHRESH) {
            int pos = atomicAdd(&g_cand_cnt[f], 1);
            if (pos < CAND_CAP) {
                g_cand_idx[f][pos] = n;
                g_cand_val[f][pos] = v;
            }
        }
    }
}

// ---------------- Kernel 2: top-8 over candidates, verify ----------------
// grid = (NN/256, FF); lane = m (coalesced adj row segments)
__global__ __launch_bounds__(256) void topk_main(const float* __restrict__ x,
                                                 const float* __restrict__ adj,
                                                 float* __restrict__ out) {
    int f = blockIdx.y;
    int m = blockIdx.x * 256 + threadIdx.x;

    int cnt = g_cand_cnt[f];
    bool col_ok = (cnt <= CAND_CAP);
    int c2 = cnt < CAND_CAP ? cnt : CAND_CAP;

    float h[KK];
#pragma unroll
    for (int j = 0; j < KK; ++j) h[j] = -FLT_MAX;

    for (int i = 0; i < c2; ++i) {
        int n = g_cand_idx[f][i];          // wave-uniform
        float xv = g_cand_val[f][i];       // wave-uniform
        float v = adj[n * NN + m] * xv;    // coalesced across lanes
        // branchless sorted-descending insert (max/min chain)
#pragma unroll
        for (int j = 0; j < KK; ++j) {
            float hi = h[j];
            float mx = fmaxf(hi, v);
            v = fminf(hi, v);
            h[j] = mx;
        }
    }

    // write output
    out[(m * 9 + 0) * FF + f] = x[m * FF + f];
#pragma unroll
    for (int j = 0; j < KK; ++j)
        out[(m * 9 + 1 + j) * FF + f] = h[j];

    // verification: all excluded products are < CTHRESH; exact iff t >= c
    bool ok = col_ok && (h[KK - 1] >= CTHRESH);
    if (!ok) {
        int pos = atomicAdd(&g_nfail, 1);
        g_fail_list[pos] = (m << 6) | f;
    }
}

// ---------------- Kernel 3: exact full-scan fixup for failed (m,f) ----------------
__global__ __launch_bounds__(256) void fixup(const float* __restrict__ x,
                                             const float* __restrict__ adj,
                                             float* __restrict__ out) {
    __shared__ float sv[NN];
    __shared__ float rmax[256];
    __shared__ int   rind[256];

    int nf = g_nfail;
    for (int e = blockIdx.x; e < nf; e += gridDim.x) {
        int mf = g_fail_list[e];
        int m = mf >> 6;
        int f = mf & 63;
        for (int n = threadIdx.x; n < NN; n += 256)
            sv[n] = adj[n * NN + m] * x[n * FF + f];
        __syncthreads();
        for (int j = 0; j < KK; ++j) {
            float best = -FLT_MAX;
            int bi = 0;
            for (int n = threadIdx.x; n < NN; n += 256) {
                if (sv[n] > best) { best = sv[n]; bi = n; }
            }
            rmax[threadIdx.x] = best;
            rind[threadIdx.x] = bi;
            __syncthreads();
            for (int s = 128; s > 0; s >>= 1) {
                if (threadIdx.x < s) {
                    if (rmax[threadIdx.x + s] > rmax[threadIdx.x]) {
                        rmax[threadIdx.x] = rmax[threadIdx.x + s];
                        rind[threadIdx.x] = rind[threadIdx.x + s];
                    }
                }
                __syncthreads();
            }
            if (threadIdx.x == 0) {
                out[(m * 9 + 1 + j) * FF + f] = rmax[0];
                sv[rind[0]] = -FLT_MAX;
            }
            __syncthreads();
        }
        __syncthreads();
    }
}

extern "C" void kernel_launch(void* const* d_in, const int* in_sizes, int n_in,
                              void* d_out, int out_size, void* d_ws, size_t ws_size,
                              hipStream_t stream) {
    const float* x   = (const float*)d_in[0];   // [2048, 64]
    const float* adj = (const float*)d_in[1];   // [2048, 2048]
    float* out = (float*)d_out;                 // [2048, 9, 64]

    build_cand<<<FF, 256, 0, stream>>>(x);

    dim3 grid2(NN / 256, FF);
    topk_main<<<grid2, 256, 0, stream>>>(x, adj, out);

    fixup<<<128, 256, 0, stream>>>(x, adj, out);
}

// Round 2
// 99.654 us; speedup vs baseline: 1.3080x; 1.3080x over previous
//
#include <hip/hip_runtime.h>
#include <hip/hip_bf16.h>
#include <float.h>

// Problem: N=2048, F=64, K=8
//   out[m,0,f]   = x[m,f]
//   out[m,1+j,f] = j-th largest over n of adj[n,m]*x[n,f], sorted descending
//
// adj in [0,1) => a product adj*x can only reach value v if x > v. Keep only
// candidates x[n,f] > 1.3 (~200/2048), SORTED DESC, so a wave can stop as
// soon as every lane's current 8th-best >= next candidate's x (all remaining
// products are <= that x). Verify exactness per (m,f) via h[7] >= 1.3; the
// (astronomically rare) failures take an inline exact full rescan.

#define NN 2048
#define FF 64
#define KK 8
#define CTHRESH 1.3f
#define CAP 512          // power of two for bitonic; P(cnt>512) ~ 0 (+23 sigma)

__device__ float g_val[FF][CAP];
__device__ int   g_idx[FF][CAP];
__device__ int   g_cnt[FF];      // padded-to-8 count actually stored
__device__ int   g_over[FF];     // 1 if candidate list overflowed CAP

// ---------- Kernel A: build + bitonic-sort (desc) per-feature candidates ----------
__global__ __launch_bounds__(256) void build_sort(const float* __restrict__ x) {
    __shared__ float sval[CAP];
    __shared__ int   sidx[CAP];
    __shared__ int   scnt;
    const int f = blockIdx.x, tid = threadIdx.x;

    if (tid == 0) scnt = 0;
    for (int i = tid; i < CAP; i += 256) { sval[i] = 0.0f; sidx[i] = 0; }
    __syncthreads();

    for (int n = tid; n < NN; n += 256) {
        float v = x[n * FF + f];
        if (v > CTHRESH) {
            int p = atomicAdd(&scnt, 1);
            if (p < CAP) { sval[p] = v; sidx[p] = n; }
        }
    }
    __syncthreads();
    const int cnt = scnt;

    // bitonic sort, descending by sval (pads=0 sink to the end; reals >= 1.3)
    for (int k = 2; k <= CAP; k <<= 1) {
        for (int j = k >> 1; j > 0; j >>= 1) {
            __syncthreads();
            for (int t = tid; t < CAP; t += 256) {
                int l = t ^ j;
                if (l > t) {
                    float a = sval[t], b = sval[l];
                    bool up = ((t & k) == 0);
                    bool sw = up ? (a < b) : (a > b);   // descending overall
                    if (sw) {
                        sval[t] = b; sval[l] = a;
                        int ti = sidx[t]; sidx[t] = sidx[l]; sidx[l] = ti;
                    }
                }
            }
        }
    }
    __syncthreads();

    int cnt_c   = cnt < CAP ? cnt : CAP;
    int cnt_pad = (cnt_c + 7) & ~7;                     // pads hold val=0, idx=0
    for (int i = tid; i < cnt_pad; i += 256) { g_val[f][i] = sval[i]; g_idx[f][i] = sidx[i]; }
    if (tid == 0) { g_cnt[f] = cnt_pad; g_over[f] = (cnt > CAP) ? 1 : 0; }
}

// ---------- Kernel B: top-8 with wave early-exit + inline exact fixup ----------
// grid = (NN/256, FF); lane = m so adj row segments are coalesced
__global__ __launch_bounds__(256) void topk(const float* __restrict__ x,
                                            const float* __restrict__ adj,
                                            float* __restrict__ out) {
    __shared__ float sval[CAP];
    __shared__ int   sidx[CAP];
    const int f = blockIdx.y;
    const int m = blockIdx.x * 256 + threadIdx.x;

    const int cnt  = g_cnt[f];
    const int over = g_over[f];
    for (int i = threadIdx.x; i < cnt; i += 256) { sval[i] = g_val[f][i]; sidx[i] = g_idx[f][i]; }
    __syncthreads();

    float h[KK];
#pragma unroll
    for (int j = 0; j < KK; ++j) h[j] = -FLT_MAX;

    for (int i = 0; i < cnt; i += 8) {
        // all remaining products <= sval[i] (sorted desc, adj < 1):
        if (__all(h[KK - 1] >= sval[i])) break;

        float v[8];
#pragma unroll
        for (int u = 0; u < 8; ++u) {
            int n = sidx[i + u];
            v[u] = adj[n * NN + m] * sval[i + u];   // 8 independent coalesced loads
        }
#pragma unroll
        for (int u = 0; u < 8; ++u) {
            float vv = v[u];
#pragma unroll
            for (int j = 0; j < KK; ++j) {
                float hi = h[j];
                float mx = fmaxf(hi, vv);
                vv = fminf(hi, vv);
                h[j] = mx;
            }
        }
    }

    // exactness certificate: every excluded product < CTHRESH <= h[7]
    bool ok = (!over) && (h[KK - 1] >= CTHRESH);
    if (!ok) {
        // exact full rescan for this (m,f) — statistically never taken
#pragma unroll
        for (int j = 0; j < KK; ++j) h[j] = -FLT_MAX;
        for (int n = 0; n < NN; ++n) {
            float vv = adj[n * NN + m] * x[n * FF + f];
#pragma unroll
            for (int j = 0; j < KK; ++j) {
                float hi = h[j];
                float mx = fmaxf(hi, vv);
                vv = fminf(hi, vv);
                h[j] = mx;
            }
        }
    }

    out[(m * 9 + 0) * FF + f] = x[m * FF + f];
#pragma unroll
    for (int j = 0; j < KK; ++j)
        out[(m * 9 + 1 + j) * FF + f] = h[j];
}

extern "C" void kernel_launch(void* const* d_in, const int* in_sizes, int n_in,
                              void* d_out, int out_size, void* d_ws, size_t ws_size,
                              hipStream_t stream) {
    const float* x   = (const float*)d_in[0];   // [2048, 64]
    const float* adj = (const float*)d_in[1];   // [2048, 2048]
    float* out = (float*)d_out;                 // [2048, 9, 64]

    build_sort<<<FF, 256, 0, stream>>>(x);

    dim3 grid2(NN / 256, FF);
    topk<<<grid2, 256, 0, stream>>>(x, adj, out);
}

// Round 3
// 96.928 us; speedup vs baseline: 1.3448x; 1.0281x over previous
//
#include <hip/hip_runtime.h>
#include <hip/hip_bf16.h>
#include <float.h>

// Problem: N=2048, F=64, K=8
//   out[m,0,f]   = x[m,f]
//   out[m,1+j,f] = j-th largest over n of adj[n,m]*x[n,f], sorted descending
//
// adj in [0,1) => a product adj*x can only reach value v if x > v. Keep only
// candidates x[n,f] > 1.3 (~200/2048), sorted desc. Each block: 4 waves over
// the same 64 m's, wave w scans sorted groups g%4==w (each subsequence is
// descending -> per-wave early exit exact), then exact tree-merge of the four
// top-8s in LDS. Certificate h[7] >= 1.3 proves excluded products can't
// matter; failures (never, statistically) take an inline exact full rescan.

#define NN 2048
#define FF 64
#define KK 8
#define CTHRESH 1.3f
#define CAP 512          // cnt ~ 198 +- 13; P(cnt > 512) ~ 0
#define SEG 4            // candidate segments == waves per block

__device__ float g_val[FF][CAP];
__device__ int   g_idx[FF][CAP];
__device__ int   g_cnt[FF];      // padded to multiple of 32
__device__ int   g_over[FF];

// ---------- Kernel A: build + rank-sort (desc) per-feature candidates ----------
__global__ __launch_bounds__(256) void build_sort(const float* __restrict__ x) {
    __shared__ float sval[CAP];
    __shared__ int   sidx[CAP];
    __shared__ int   scnt;
    const int f = blockIdx.x, tid = threadIdx.x;

    if (tid == 0) scnt = 0;
    __syncthreads();

    for (int n = tid; n < NN; n += 256) {
        float v = x[n * FF + f];
        if (v > CTHRESH) {
            int p = atomicAdd(&scnt, 1);
            if (p < CAP) { sval[p] = v; sidx[p] = n; }
        }
    }
    __syncthreads();
    const int cnt = scnt < CAP ? scnt : CAP;
    const int cnt_pad = (cnt + 31) & ~31;

    // exact rank sort (desc, ties by original slot): ~cnt^2 LDS-broadcast cmps
    for (int i = tid; i < cnt; i += 256) {
        float vi = sval[i];
        int r = 0;
        for (int j = 0; j < cnt; ++j) {
            float vj = sval[j];
            r += (vj > vi) || (vj == vi && j < i);
        }
        g_val[f][r] = vi;
        g_idx[f][r] = sidx[i];
    }
    // zero pads (val=0 products can never displace a certified top-8)
    for (int i = cnt + tid; i < cnt_pad; i += 256) { g_val[f][i] = 0.0f; g_idx[f][i] = 0; }
    if (tid == 0) { g_cnt[f] = cnt_pad; g_over[f] = (scnt > CAP) ? 1 : 0; }
}

// branchless sorted-desc insert of v into h[0..7]
__device__ __forceinline__ void insert8(float (&h)[KK], float v) {
#pragma unroll
    for (int j = 0; j < KK; ++j) {
        float hi = h[j];
        float mx = fmaxf(hi, v);
        v = fminf(hi, v);
        h[j] = mx;
    }
}

// ---------- Kernel B: segmented top-8 + in-block tree merge ----------
// grid = (NN/64, FF); block = 256 = 4 waves, all covering the same 64 m's
__global__ __launch_bounds__(256) void topk(const float* __restrict__ x,
                                            const float* __restrict__ adj,
                                            float* __restrict__ out) {
    __shared__ float hm[SEG][KK][64];          // 8 KB
    const int f    = blockIdx.y;
    const int wave = threadIdx.x >> 6;
    const int lane = threadIdx.x & 63;
    const int m    = blockIdx.x * 64 + lane;

    const int ngroups = g_cnt[f] >> 3;

    float h[KK];
#pragma unroll
    for (int j = 0; j < KK; ++j) h[j] = -FLT_MAX;

    for (int g = wave; g < ngroups; g += SEG) {
        const int i = g * 8;
        float head = g_val[f][i];
        // this wave's remaining candidates all have x <= head => products < head
        if (__all(h[KK - 1] >= head)) break;

        float v[8];
#pragma unroll
        for (int u = 0; u < 8; ++u) {
            int n = g_idx[f][i + u];
            v[u] = adj[n * NN + m] * g_val[f][i + u];   // coalesced across lanes
        }
#pragma unroll
        for (int u = 0; u < 8; ++u) insert8(h, v[u]);
    }

#pragma unroll
    for (int j = 0; j < KK; ++j) hm[wave][j][lane] = h[j];
    __syncthreads();

    // level 1: wave0 merges seg0+seg1, wave1 merges seg2+seg3
    if (wave < 2) {
        float a[KK];
#pragma unroll
        for (int j = 0; j < KK; ++j) a[j] = hm[wave * 2][j][lane];
#pragma unroll
        for (int u = 0; u < KK; ++u) insert8(a, hm[wave * 2 + 1][u][lane]);
#pragma unroll
        for (int j = 0; j < KK; ++j) hm[wave * 2][j][lane] = a[j];
    }
    __syncthreads();

    // level 2: wave0 merges the two results, certifies, writes out
    if (wave == 0) {
        float a[KK];
#pragma unroll
        for (int j = 0; j < KK; ++j) a[j] = hm[0][j][lane];
#pragma unroll
        for (int u = 0; u < KK; ++u) insert8(a, hm[2][u][lane]);

        // exactness certificate: every excluded product < CTHRESH <= a[7]
        bool ok = (!g_over[f]) && (a[KK - 1] >= CTHRESH);
        if (!ok) {
            // exact full rescan for this (m,f) — statistically never taken
#pragma unroll
            for (int j = 0; j < KK; ++j) a[j] = -FLT_MAX;
            for (int n = 0; n < NN; ++n)
                insert8(a, adj[n * NN + m] * x[n * FF + f]);
        }

        out[(m * 9 + 0) * FF + f] = x[m * FF + f];
#pragma unroll
        for (int j = 0; j < KK; ++j)
            out[(m * 9 + 1 + j) * FF + f] = a[j];
    }
}

extern "C" void kernel_launch(void* const* d_in, const int* in_sizes, int n_in,
                              void* d_out, int out_size, void* d_ws, size_t ws_size,
                              hipStream_t stream) {
    const float* x   = (const float*)d_in[0];   // [2048, 64]
    const float* adj = (const float*)d_in[1];   // [2048, 2048]
    float* out = (float*)d_out;                 // [2048, 9, 64]

    build_sort<<<FF, 256, 0, stream>>>(x);

    dim3 grid2(NN / 64, FF);
    topk<<<grid2, 256, 0, stream>>>(x, adj, out);
}

// Round 4
// 92.970 us; speedup vs baseline: 1.4021x; 1.0426x over previous
//
#include <hip/hip_runtime.h>
#include <hip/hip_bf16.h>
#include <float.h>

// Problem: N=2048, F=64, K=8
//   out[m,0,f]   = x[m,f]
//   out[m,1+j,f] = j-th largest over n of adj[n,m]*x[n,f], sorted descending
//
// adj in [0,1) => a product adj*x can only reach value v if x > v. Keep only
// candidates x[n,f] > 1.3 (~200/2048), sorted desc. topk: 4 waves per block
// over the same 64 m's, wave w scans sorted groups g%4==w; waves share a
// monotone per-m floor (max of any wave's 8th-best, LDS atomicMax) so every
// wave exits as early as the best bound allows. Exact tree-merge of the four
// top-8s. Certificate h[7] >= 1.3 proves excluded (x<=1.3) products can't
// matter; failures (statistically never) take an inline exact full rescan.

#define NN 2048
#define FF 64
#define KK 8
#define CTHRESH 1.3f
#define CAP 512          // cnt ~ 198 +- 13; P(cnt > 512) ~ 0
#define SEG 4            // candidate segments == waves per block

__device__ float g_val[FF][CAP];
__device__ int   g_idx[FF][CAP];
__device__ int   g_cnt[FF];      // padded to multiple of 8
__device__ int   g_over[FF];

// ---------- Kernel A: build + rank-sort (desc) per-feature candidates ----------
__global__ __launch_bounds__(256) void build_sort(const float* __restrict__ x) {
    __shared__ float sval[CAP];
    __shared__ int   sidx[CAP];
    __shared__ int   scnt;
    const int f = blockIdx.x, tid = threadIdx.x;

    if (tid == 0) scnt = 0;
    __syncthreads();

    for (int n = tid; n < NN; n += 256) {
        float v = x[n * FF + f];
        if (v > CTHRESH) {
            int p = atomicAdd(&scnt, 1);
            if (p < CAP) { sval[p] = v; sidx[p] = n; }
        }
    }
    __syncthreads();
    const int cnt = scnt < CAP ? scnt : CAP;
    const int cnt_pad = (cnt + 7) & ~7;

    // exact rank sort (desc, ties by original slot): ~cnt^2 LDS-broadcast cmps
    for (int i = tid; i < cnt; i += 256) {
        float vi = sval[i];
        int r = 0;
        for (int j = 0; j < cnt; ++j) {
            float vj = sval[j];
            r += (vj > vi) || (vj == vi && j < i);
        }
        g_val[f][r] = vi;
        g_idx[f][r] = sidx[i];
    }
    // zero pads (val=0 products can never displace a certified top-8)
    for (int i = cnt + tid; i < cnt_pad; i += 256) { g_val[f][i] = 0.0f; g_idx[f][i] = 0; }
    if (tid == 0) { g_cnt[f] = cnt_pad; g_over[f] = (scnt > CAP) ? 1 : 0; }
}

// branchless sorted-desc insert of v into h[0..7]
__device__ __forceinline__ void insert8(float (&h)[KK], float v) {
#pragma unroll
    for (int j = 0; j < KK; ++j) {
        float hi = h[j];
        float mx = fmaxf(hi, v);
        v = fminf(hi, v);
        h[j] = mx;
    }
}

// ---------- Kernel B: segmented top-8, shared floor, tree merge ----------
// grid = (NN/64, FF); block = 256 = 4 waves, all covering the same 64 m's
__global__ __launch_bounds__(256) void topk(const float* __restrict__ x,
                                            const float* __restrict__ adj,
                                            float* __restrict__ out) {
    __shared__ float    sval[CAP];
    __shared__ int      sidx[CAP];
    __shared__ unsigned sfloor[64];            // nonneg float bits, atomicMax
    __shared__ float    hm[SEG][KK][64];       // 8 KB
    __shared__ float    res[9][64];            // staged output rows

    const int f    = blockIdx.y;
    const int wave = threadIdx.x >> 6;
    const int lane = threadIdx.x & 63;
    const int m0   = blockIdx.x * 64;
    const int m    = m0 + lane;

    const int cnt     = g_cnt[f];
    const int ngroups = cnt >> 3;

    for (int i = threadIdx.x; i < cnt; i += 256) { sval[i] = g_val[f][i]; sidx[i] = g_idx[f][i]; }
    if (threadIdx.x < 64) sfloor[threadIdx.x] = 0u;
    __syncthreads();

    float h[KK];
#pragma unroll
    for (int j = 0; j < KK; ++j) h[j] = -FLT_MAX;

    for (int g = wave; g < ngroups; g += SEG) {
        const int i = g * 8;
        float head = sval[i];
        // all remaining products for this wave are < head; if every lane's
        // shared floor (some wave's 8th-best for this m) already >= head,
        // nothing left here can enter the merged top-8.
        if (__all(__uint_as_float(sfloor[lane]) >= head)) break;

        float v[8];
#pragma unroll
        for (int u = 0; u < 8; ++u) {
            int n = sidx[i + u];
            v[u] = adj[n * NN + m] * sval[i + u];   // coalesced across lanes
        }
#pragma unroll
        for (int u = 0; u < 8; ++u) insert8(h, v[u]);

        // publish this wave's floor (products >= 0, so float bits order as uint)
        atomicMax(&sfloor[lane], __float_as_uint(fmaxf(h[KK - 1], 0.0f)));
    }

#pragma unroll
    for (int j = 0; j < KK; ++j) hm[wave][j][lane] = h[j];
    __syncthreads();

    // level 1: wave0 merges seg0+seg1, wave1 merges seg2+seg3
    if (wave < 2) {
        float a[KK];
#pragma unroll
        for (int j = 0; j < KK; ++j) a[j] = hm[wave * 2][j][lane];
#pragma unroll
        for (int u = 0; u < KK; ++u) insert8(a, hm[wave * 2 + 1][u][lane]);
#pragma unroll
        for (int j = 0; j < KK; ++j) hm[wave * 2][j][lane] = a[j];
    }
    __syncthreads();

    // level 2: wave0 merges the two results, certifies, stages output
    if (wave == 0) {
        float a[KK];
#pragma unroll
        for (int j = 0; j < KK; ++j) a[j] = hm[0][j][lane];
#pragma unroll
        for (int u = 0; u < KK; ++u) insert8(a, hm[2][u][lane]);

        // exactness certificate: every excluded product < CTHRESH <= a[7]
        bool ok = (!g_over[f]) && (a[KK - 1] >= CTHRESH);
        if (!ok) {
            // exact full rescan for this (m,f) — statistically never taken
#pragma unroll
            for (int j = 0; j < KK; ++j) a[j] = -FLT_MAX;
            for (int n = 0; n < NN; ++n)
                insert8(a, adj[n * NN + m] * x[n * FF + f]);
        }

        res[0][lane] = x[m * FF + f];
#pragma unroll
        for (int j = 0; j < KK; ++j) res[1 + j][lane] = a[j];
    }
    __syncthreads();

    // distributed store of the block's 576 output words
    for (int e = threadIdx.x; e < 9 * 64; e += 256) {
        int r  = e >> 6;
        int ml = e & 63;
        out[((m0 + ml) * 9 + r) * FF + f] = res[r][ml];
    }
}

extern "C" void kernel_launch(void* const* d_in, const int* in_sizes, int n_in,
                              void* d_out, int out_size, void* d_ws, size_t ws_size,
                              hipStream_t stream) {
    const float* x   = (const float*)d_in[0];   // [2048, 64]
    const float* adj = (const float*)d_in[1];   // [2048, 2048]
    float* out = (float*)d_out;                 // [2048, 9, 64]

    build_sort<<<FF, 256, 0, stream>>>(x);

    dim3 grid2(NN / 64, FF);
    topk<<<grid2, 256, 0, stream>>>(x, adj, out);
}

// Round 5
// 89.960 us; speedup vs baseline: 1.4490x; 1.0335x over previous
//
#include <hip/hip_runtime.h>
#include <hip/hip_bf16.h>
#include <float.h>

// Problem: N=2048, F=64, K=8
//   out[m,0,f]   = x[m,f]
//   out[m,1+j,f] = j-th largest over n of adj[n,m]*x[n,f], sorted descending
//
// adj in [0,1) => a product adj*x can only reach value v if x > v. Keep only
// candidates x[n,f] > 1.3 (~200/2048), sorted desc. topk: 4 waves per block
// over the same 64 m's; wave w scans sorted groups g%4==w with a shared
// monotone per-m floor (LDS atomicMax of any wave's 8th-best) for early exit.
// Candidate metadata is read via readfirstlane-scalarized (SMEM) loads; adj
// loads are prefetched one group ahead; per-group top-8 update is a Batcher
// sort-8 + bitonic top-8 merge (70 ops vs 128 for insertion).
// Certificate h[7] >= 1.3 proves excluded (x<=1.3) products can't matter;
// failures (statistically never) take an inline exact full rescan.

#define NN 2048
#define FF 64
#define KK 8
#define CTHRESH 1.3f
#define CAP 512          // cnt ~ 198 +- 13; P(cnt > 512) ~ 0
#define SEG 4            // candidate segments == waves per block

__device__ float g_val[FF][CAP];
__device__ int   g_idx[FF][CAP];
__device__ int   g_cnt[FF];      // padded to multiple of 8
__device__ int   g_over[FF];

// ---------- Kernel A: build + rank-sort (desc) per-feature candidates ----------
__global__ __launch_bounds__(256) void build_sort(const float* __restrict__ x) {
    __shared__ float sval[CAP];
    __shared__ int   sidx[CAP];
    __shared__ int   scnt;
    const int f = blockIdx.x, tid = threadIdx.x;

    if (tid == 0) scnt = 0;
    __syncthreads();

    for (int n = tid; n < NN; n += 256) {
        float v = x[n * FF + f];
        if (v > CTHRESH) {
            int p = atomicAdd(&scnt, 1);
            if (p < CAP) { sval[p] = v; sidx[p] = n; }
        }
    }
    __syncthreads();
    const int cnt = scnt < CAP ? scnt : CAP;
    const int cnt_pad = (cnt + 7) & ~7;

    // exact rank sort (desc, ties by original slot): ~cnt^2 LDS-broadcast cmps
    for (int i = tid; i < cnt; i += 256) {
        float vi = sval[i];
        int r = 0;
        for (int j = 0; j < cnt; ++j) {
            float vj = sval[j];
            r += (vj > vi) || (vj == vi && j < i);
        }
        g_val[f][r] = vi;
        g_idx[f][r] = sidx[i];
    }
    // zero pads (val=0 products can never displace a certified top-8)
    for (int i = cnt + tid; i < cnt_pad; i += 256) { g_val[f][i] = 0.0f; g_idx[f][i] = 0; }
    if (tid == 0) { g_cnt[f] = cnt_pad; g_over[f] = (scnt > CAP) ? 1 : 0; }
}

// ---------- sorting primitives (descending) ----------
__device__ __forceinline__ void cas(float& a, float& b) {
    float hi = fmaxf(a, b), lo = fminf(a, b);
    a = hi; b = lo;
}

// Batcher odd-even mergesort, 8 elements, 19 CAS, descending
__device__ __forceinline__ void sort8(float (&v)[8]) {
    cas(v[0],v[1]); cas(v[2],v[3]); cas(v[4],v[5]); cas(v[6],v[7]);
    cas(v[0],v[2]); cas(v[1],v[3]); cas(v[4],v[6]); cas(v[5],v[7]);
    cas(v[1],v[2]); cas(v[5],v[6]);
    cas(v[0],v[4]); cas(v[1],v[5]); cas(v[2],v[6]); cas(v[3],v[7]);
    cas(v[2],v[4]); cas(v[3],v[5]);
    cas(v[1],v[2]); cas(v[3],v[4]); cas(v[5],v[6]);
}

// h, c sorted desc -> h = top-8 of union, sorted desc (bitonic merge)
__device__ __forceinline__ void merge_top8(float (&h)[8], const float (&c)[8]) {
    float t[8];
#pragma unroll
    for (int i = 0; i < 8; ++i) t[i] = fmaxf(h[i], c[7 - i]);   // bitonic, top-8
    cas(t[0],t[4]); cas(t[1],t[5]); cas(t[2],t[6]); cas(t[3],t[7]);
    cas(t[0],t[2]); cas(t[1],t[3]); cas(t[4],t[6]); cas(t[5],t[7]);
    cas(t[0],t[1]); cas(t[2],t[3]); cas(t[4],t[5]); cas(t[6],t[7]);
#pragma unroll
    for (int i = 0; i < 8; ++i) h[i] = t[i];
}

// branchless sorted-desc insert (used only by the never-taken exact rescan)
__device__ __forceinline__ void insert8(float (&h)[KK], float v) {
#pragma unroll
    for (int j = 0; j < KK; ++j) {
        float hi = h[j];
        float mx = fmaxf(hi, v);
        v = fminf(hi, v);
        h[j] = mx;
    }
}

// ---------- Kernel B: segmented top-8, shared floor, prefetch, tree merge ----------
// grid = (NN/64, FF); block = 256 = 4 waves, all covering the same 64 m's
__global__ __launch_bounds__(256) void topk(const float* __restrict__ x,
                                            const float* __restrict__ adj,
                                            float* __restrict__ out) {
    __shared__ unsigned sfloor[64];            // nonneg float bits, atomicMax
    __shared__ float    hm[SEG][KK][64];       // 8 KB
    __shared__ float    res[9][64];            // staged output rows

    const int f    = blockIdx.y;
    const int wave = threadIdx.x >> 6;
    const int lane = threadIdx.x & 63;
    const int m0   = blockIdx.x * 64;
    const int m    = m0 + lane;

    if (threadIdx.x < 64) sfloor[threadIdx.x] = 0u;
    __syncthreads();

    const int ngroups = g_cnt[f] >> 3;

    float h[KK];
#pragma unroll
    for (int j = 0; j < KK; ++j) h[j] = -FLT_MAX;

    float A[8], X[8];                          // prefetched adj values / x-vals
    int g = wave;
    bool active = (g < ngroups);
    if (active) {
        const int ib = __builtin_amdgcn_readfirstlane(g * 8);
#pragma unroll
        for (int u = 0; u < 8; ++u) {
            int n = g_idx[f][ib + u];          // uniform -> scalar load
            X[u] = g_val[f][ib + u];           // uniform -> scalar load
            A[u] = adj[(size_t)n * NN + m];    // s-base + v-offset, coalesced
        }
    }

    while (active) {
        const int gn = g + SEG;
        bool more = (gn < ngroups);
        if (more) {
            // remaining candidates for this wave all have x <= head; products
            // are strictly < x (adj < 1), so floor >= head certifies them out.
            float head = g_val[f][__builtin_amdgcn_readfirstlane(gn * 8)];
            if (__all(__uint_as_float(sfloor[lane]) >= head)) more = false;
        }

        float B[8], Y[8];
        if (more) {
            const int ib = __builtin_amdgcn_readfirstlane(gn * 8);
#pragma unroll
            for (int u = 0; u < 8; ++u) {
                int n = g_idx[f][ib + u];
                Y[u] = g_val[f][ib + u];
                B[u] = adj[(size_t)n * NN + m];   // prefetch next group
            }
        }

        float p[8];
#pragma unroll
        for (int u = 0; u < 8; ++u) p[u] = A[u] * X[u];
        sort8(p);
        merge_top8(h, p);

        // publish this wave's floor (products >= 0 => float bits order as uint)
        atomicMax(&sfloor[lane], __float_as_uint(fmaxf(h[KK - 1], 0.0f)));

        if (more) {
#pragma unroll
            for (int u = 0; u < 8; ++u) { A[u] = B[u]; X[u] = Y[u]; }
        }
        g = gn;
        active = more;
    }

#pragma unroll
    for (int j = 0; j < KK; ++j) hm[wave][j][lane] = h[j];
    __syncthreads();

    // level 1: wave0 merges seg0+seg1, wave1 merges seg2+seg3 (rows sorted)
    if (wave < 2) {
        float a[KK], c[KK];
#pragma unroll
        for (int j = 0; j < KK; ++j) a[j] = hm[wave * 2][j][lane];
#pragma unroll
        for (int j = 0; j < KK; ++j) c[j] = hm[wave * 2 + 1][j][lane];
        merge_top8(a, c);
#pragma unroll
        for (int j = 0; j < KK; ++j) hm[wave * 2][j][lane] = a[j];
    }
    __syncthreads();

    // level 2: wave0 merges the two results, certifies, stages output
    if (wave == 0) {
        float a[KK], c[KK];
#pragma unroll
        for (int j = 0; j < KK; ++j) a[j] = hm[0][j][lane];
#pragma unroll
        for (int j = 0; j < KK; ++j) c[j] = hm[2][j][lane];
        merge_top8(a, c);

        // exactness certificate: every excluded product < CTHRESH <= a[7]
        bool ok = (!g_over[f]) && (a[KK - 1] >= CTHRESH);
        if (!ok) {
            // exact full rescan for this (m,f) — statistically never taken
#pragma unroll
            for (int j = 0; j < KK; ++j) a[j] = -FLT_MAX;
            for (int n = 0; n < NN; ++n)
                insert8(a, adj[n * NN + m] * x[n * FF + f]);
        }

        res[0][lane] = x[m * FF + f];
#pragma unroll
        for (int j = 0; j < KK; ++j) res[1 + j][lane] = a[j];
    }
    __syncthreads();

    // distributed store of the block's 576 output words
    for (int e = threadIdx.x; e < 9 * 64; e += 256) {
        int r  = e >> 6;
        int ml = e & 63;
        out[((m0 + ml) * 9 + r) * FF + f] = res[r][ml];
    }
}

extern "C" void kernel_launch(void* const* d_in, const int* in_sizes, int n_in,
                              void* d_out, int out_size, void* d_ws, size_t ws_size,
                              hipStream_t stream) {
    const float* x   = (const float*)d_in[0];   // [2048, 64]
    const float* adj = (const float*)d_in[1];   // [2048, 2048]
    float* out = (float*)d_out;                 // [2048, 9, 64]

    build_sort<<<FF, 256, 0, stream>>>(x);

    dim3 grid2(NN / 64, FF);
    topk<<<grid2, 256, 0, stream>>>(x, adj, out);
}

// Round 7
// 89.241 us; speedup vs baseline: 1.4606x; 1.0081x over previous
//
#include <hip/hip_runtime.h>
#include <float.h>

// Problem: N=2048, F=64, K=8
//   out[m,0,f]   = x[m,f]
//   out[m,1+j,f] = j-th largest over n of adj[n,m]*x[n,f], sorted descending
//
// adj in [0,1) => product < x. Keep candidates x[n,f] > 1.3 (~198/2048),
// classified into 9 value buckets (no sort). Bucket b's upper edge E[b] is
// an exact bound on any product from it, so a wave may stop when every
// lane's shared floor (LDS atomicMax of any wave's 8th-best) >= E[b] —
// all remaining buckets have smaller edges. Certificate h[7] >= 1.3 covers
// the unstored x<=1.3 tail; capacity overflow (never, ~8 sigma) falls back
// to an inline exact full rescan. Pad slots are (val=0, idx=0): product 0,
// address valid.

#define NN 2048
#define FF 64
#define KK 8
#define CTHRESH 1.30f
#define NB 9
#define TOT 544          // sum of bucket capacities

// bucket capacities / offsets / upper bounds (counts ~N(mu, sqrt(mu)), caps ~ mu+8sigma)
__device__ __constant__ int   d_cap[NB]  = {40, 40, 48, 56, 56, 64, 72, 80, 88};
__device__ __constant__ int   d_off[NB]  = {0, 40, 80, 128, 184, 240, 304, 376, 456};
__device__ __constant__ float d_bnd[NB]  = {FLT_MAX, 2.50f, 2.25f, 2.05f, 1.90f,
                                            1.77f, 1.65f, 1.54f, 1.42f};

__device__ int2 g_pack[FF][TOT];   // (float bits of x-val, n index)
__device__ int  g_bcnt[FF][NB];
__device__ int  g_over[FF];

// ---------- Kernel A: classify x-column into buckets (no sort) ----------
__global__ __launch_bounds__(256) void build_buckets(const float* __restrict__ x) {
    __shared__ int  bcnt[NB];
    __shared__ int2 sp[TOT];
    const int f = blockIdx.x, tid = threadIdx.x;

    if (tid < NB) bcnt[tid] = 0;
    for (int i = tid; i < TOT; i += 256) sp[i] = make_int2(0, 0);  // safe pads
    __syncthreads();

    for (int n = tid; n < NN; n += 256) {
        float v = x[n * FF + f];
        if (v > CTHRESH) {
            int b = (v <= 2.50f) + (v <= 2.25f) + (v <= 2.05f) + (v <= 1.90f)
                  + (v <= 1.77f) + (v <= 1.65f) + (v <= 1.54f) + (v <= 1.42f);
            int p = atomicAdd(&bcnt[b], 1);
            if (p < d_cap[b]) sp[d_off[b] + p] = make_int2(__float_as_int(v), n);
        }
    }
    __syncthreads();

    for (int i = tid; i < TOT; i += 256) g_pack[f][i] = sp[i];
    if (tid < NB) {
        int c = bcnt[tid];
        g_bcnt[f][tid] = c < d_cap[tid] ? c : d_cap[tid];
    }
    if (tid == 32) {
        int ov = 0;
#pragma unroll
        for (int b = 0; b < NB; ++b) ov |= (bcnt[b] > d_cap[b]);
        g_over[f] = ov;           // recomputed fresh every call
    }
}

// ---------- sorting primitives (descending) ----------
__device__ __forceinline__ void cas(float& a, float& b) {
    float hi = fmaxf(a, b), lo = fminf(a, b);
    a = hi; b = lo;
}

// Batcher odd-even mergesort, 8 elements, 19 CAS, descending
__device__ __forceinline__ void sort8(float (&v)[8]) {
    cas(v[0],v[1]); cas(v[2],v[3]); cas(v[4],v[5]); cas(v[6],v[7]);
    cas(v[0],v[2]); cas(v[1],v[3]); cas(v[4],v[6]); cas(v[5],v[7]);
    cas(v[1],v[2]); cas(v[5],v[6]);
    cas(v[0],v[4]); cas(v[1],v[5]); cas(v[2],v[6]); cas(v[3],v[7]);
    cas(v[2],v[4]); cas(v[3],v[5]);
    cas(v[1],v[2]); cas(v[3],v[4]); cas(v[5],v[6]);
}

// h, c sorted desc -> h = top-8 of union, sorted desc (bitonic merge)
__device__ __forceinline__ void merge_top8(float (&h)[8], const float (&c)[8]) {
    float t[8];
#pragma unroll
    for (int i = 0; i < 8; ++i) t[i] = fmaxf(h[i], c[7 - i]);
    cas(t[0],t[4]); cas(t[1],t[5]); cas(t[2],t[6]); cas(t[3],t[7]);
    cas(t[0],t[2]); cas(t[1],t[3]); cas(t[4],t[6]); cas(t[5],t[7]);
    cas(t[0],t[1]); cas(t[2],t[3]); cas(t[4],t[5]); cas(t[6],t[7]);
#pragma unroll
    for (int i = 0; i < 8; ++i) h[i] = t[i];
}

// branchless sorted-desc insert (only the never-taken exact rescan)
__device__ __forceinline__ void insert8(float (&h)[KK], float v) {
#pragma unroll
    for (int j = 0; j < KK; ++j) {
        float hi = h[j];
        float mx = fmaxf(hi, v);
        v = fminf(hi, v);
        h[j] = mx;
    }
}

// ---------- Kernel B: bucket-walk top-8, shared floor, tree merge ----------
// grid = (NN/64, FF); block = 256 = 4 waves over the same 64 m's
__global__ __launch_bounds__(256) void topk(const float* __restrict__ x,
                                            const float* __restrict__ adj,
                                            float* __restrict__ out) {
    __shared__ int2     sc[TOT];               // staged candidate stream
    __shared__ unsigned sfloor[64];            // nonneg float bits, atomicMax
    __shared__ float    hm[4][KK][64];         // 8 KB
    __shared__ float    res[9][64];            // staged output rows

    const int f    = blockIdx.y;
    const int wave = threadIdx.x >> 6;
    const int lane = threadIdx.x & 63;
    const int m0   = blockIdx.x * 64;
    const int m    = m0 + lane;

    for (int i = threadIdx.x; i < TOT; i += 256) sc[i] = g_pack[f][i];
    if (threadIdx.x < 64) sfloor[threadIdx.x] = 0u;

    int cnt[NB];
#pragma unroll
    for (int b = 0; b < NB; ++b) cnt[b] = g_bcnt[f][b];   // uniform -> scalar
    const int over = g_over[f];
    __syncthreads();

    float h[KK];
#pragma unroll
    for (int j = 0; j < KK; ++j) h[j] = -FLT_MAX;

    int  cum  = 0;
    bool done = false;
#pragma unroll
    for (int b = 0; b < NB; ++b) {
        if (done) break;
        const float bound = d_bnd[b];
        const int   cb    = cnt[b];
        const int   ng    = (cb + 7) >> 3;
        const int   base  = d_off[b];
        for (int j = (wave - cum) & 3; j < ng; j += 4) {
            // every product in this & later buckets is < bound
            if (__all(__uint_as_float(sfloor[lane]) >= bound)) { done = true; break; }
            const int s = base + j * 8;
            float p[8];
#pragma unroll
            for (int u = 0; u < 8; ++u) {
                int2 cv  = sc[s + u];                             // LDS broadcast
                int  n   = __builtin_amdgcn_readfirstlane(cv.y);  // s-base adj load
                float xv = __int_as_float(cv.x);                  // pads: 0.0f
                p[u] = adj[(size_t)n * NN + m] * xv;              // coalesced
            }
            sort8(p);
            merge_top8(h, p);
            atomicMax(&sfloor[lane], __float_as_uint(fmaxf(h[KK - 1], 0.0f)));
        }
        cum += ng;
    }

#pragma unroll
    for (int j = 0; j < KK; ++j) hm[wave][j][lane] = h[j];
    __syncthreads();

    // level 1: wave0 merges seg0+seg1, wave1 merges seg2+seg3 (rows sorted)
    if (wave < 2) {
        float a[KK], c[KK];
#pragma unroll
        for (int j = 0; j < KK; ++j) a[j] = hm[wave * 2][j][lane];
#pragma unroll
        for (int j = 0; j < KK; ++j) c[j] = hm[wave * 2 + 1][j][lane];
        merge_top8(a, c);
#pragma unroll
        for (int j = 0; j < KK; ++j) hm[wave * 2][j][lane] = a[j];
    }
    __syncthreads();

    // level 2: wave0 merges, certifies, stages output
    if (wave == 0) {
        float a[KK], c[KK];
#pragma unroll
        for (int j = 0; j < KK; ++j) a[j] = hm[0][j][lane];
#pragma unroll
        for (int j = 0; j < KK; ++j) c[j] = hm[2][j][lane];
        merge_top8(a, c);

        // certificate: every excluded product < CTHRESH <= a[7]
        bool ok = (!over) && (a[KK - 1] >= CTHRESH);
        if (!ok) {
            // exact full rescan — statistically never taken
#pragma unroll
            for (int j = 0; j < KK; ++j) a[j] = -FLT_MAX;
            for (int n = 0; n < NN; ++n)
                insert8(a, adj[(size_t)n * NN + m] * x[n * FF + f]);
        }

        res[0][lane] = x[m * FF + f];
#pragma unroll
        for (int j = 0; j < KK; ++j) res[1 + j][lane] = a[j];
    }
    __syncthreads();

    // distributed store of the block's 576 output words
    for (int e = threadIdx.x; e < 9 * 64; e += 256) {
        int r  = e >> 6;
        int ml = e & 63;
        out[((m0 + ml) * 9 + r) * FF + f] = res[r][ml];
    }
}

extern "C" void kernel_launch(void* const* d_in, const int* in_sizes, int n_in,
                              void* d_out, int out_size, void* d_ws, size_t ws_size,
                              hipStream_t stream) {
    const float* x   = (const float*)d_in[0];   // [2048, 64]
    const float* adj = (const float*)d_in[1];   // [2048, 2048]
    float* out = (float*)d_out;                 // [2048, 9, 64]

    build_buckets<<<FF, 256, 0, stream>>>(x);

    dim3 grid2(NN / 64, FF);
    topk<<<grid2, 256, 0, stream>>>(x, adj, out);
}